// Round 7
// baseline (542.670 us; speedup 1.0000x reference)
//
#include <hip/hip_runtime.h>
#include <hip/hip_cooperative_groups.h>
#include <hip/hip_bf16.h>
#include <stdint.h>

namespace cg = cooperative_groups;

#define BM 128
#define BN 128

typedef __attribute__((ext_vector_type(8))) short bf16x8;
typedef __attribute__((ext_vector_type(4))) float floatx4;

// ---- helpers ------------------------------------------------------------

__device__ __forceinline__ unsigned short f2bf(float f) {
    unsigned int x;
    __builtin_memcpy(&x, &f, 4);
    unsigned int r = (x + 0x7fffu + ((x >> 16) & 1u)) >> 16;  // RNE
    return (unsigned short)r;
}

__device__ __forceinline__ float bf2f_hi(unsigned int u_hi_masked) {
    float f;
    __builtin_memcpy(&f, &u_hi_masked, 4);
    return f;
}

// async global->LDS, 16B per lane.  LDS dest must be wave-uniform base + lane*16.
__device__ __forceinline__ void async_copy16(const void* g, void* l) {
    __builtin_amdgcn_global_load_lds(
        (const __attribute__((address_space(1))) void*)(uintptr_t)g,
        (__attribute__((address_space(3))) void*)(uint32_t)(uintptr_t)l,
        16, 0, 0);
}

// ---- GEMM core: C[m][n] = scale * sum_k A[m][k] * Bt[n][k] --------------
// m97-style: 128x128 tile, 4 waves (2x2), 16x16x32 bf16 MFMA,
// global_load_lds width-16 staging into unpadded row-major LDS [row][BKT]
// (layout = lane order, a hard requirement).  BKT = 32 (16KB, coop-friendly)
// or 64 (32KB, fastest standalone).

template <int BKT>
__device__ __forceinline__ void gemm_core(unsigned short* As, unsigned short* Bs,
                                          const unsigned short* __restrict__ A,
                                          int lda,
                                          const unsigned short* __restrict__ B,
                                          int ldb, void* __restrict__ C,
                                          int ldc, bool out_bf16, int kend,
                                          float scale, int m0, int n0) {
    constexpr int CPR = BKT / 8;  // 16B chunks per tile row
    int tid = threadIdx.x;
    int lane = tid & 63;
    int wave = tid >> 6;
    int wm = (wave >> 1) * 64;
    int wn = (wave & 1) * 64;
    int fr = lane & 15;  // fragment row (m) / col (n)
    int kq = lane >> 4;  // k-quad

    floatx4 acc[4][4] = {};

    for (int k0 = 0; k0 < kend; k0 += BKT) {
#pragma unroll
        for (int q = 0; q < BKT / 16; q++) {
            int c = tid + q * 256;
            int r = c / CPR, ko = (c % CPR) * 8;
            async_copy16(A + (size_t)(m0 + r) * lda + k0 + ko, &As[c * 8]);
            async_copy16(B + (size_t)(n0 + r) * ldb + k0 + ko, &Bs[c * 8]);
        }
        __syncthreads();  // drains vmcnt before LDS reads

#pragma unroll
        for (int kh = 0; kh < BKT / 32; kh++) {
            int kc = kh * 4 + kq;
            bf16x8 af[4], bfg[4];
#pragma unroll
            for (int mi = 0; mi < 4; mi++)
                af[mi] = *(const bf16x8*)&As[(wm + mi * 16 + fr) * BKT + kc * 8];
#pragma unroll
            for (int ni = 0; ni < 4; ni++)
                bfg[ni] = *(const bf16x8*)&Bs[(wn + ni * 16 + fr) * BKT + kc * 8];
#pragma unroll
            for (int mi = 0; mi < 4; mi++)
#pragma unroll
                for (int ni = 0; ni < 4; ni++)
                    acc[mi][ni] = __builtin_amdgcn_mfma_f32_16x16x32_bf16(
                        af[mi], bfg[ni], acc[mi][ni], 0, 0, 0);
        }
        __syncthreads();  // protect LDS before next stage
    }

    // epilogue: C/D layout col=lane&15, row=(lane>>4)*4+reg  (m89/m91-verified)
    int col0 = n0 + wn + fr;
    int rbase = m0 + wm + kq * 4;
    if (out_bf16) {
        unsigned short* Cb = (unsigned short*)C;
#pragma unroll
        for (int mi = 0; mi < 4; mi++)
#pragma unroll
            for (int ni = 0; ni < 4; ni++)
#pragma unroll
                for (int r = 0; r < 4; r++)
                    Cb[(size_t)(rbase + mi * 16 + r) * ldc + col0 + ni * 16] =
                        f2bf(acc[mi][ni][r] * scale);
    } else {
        float* Cb = (float*)C;
#pragma unroll
        for (int mi = 0; mi < 4; mi++)
#pragma unroll
            for (int ni = 0; ni < 4; ni++)
#pragma unroll
                for (int r = 0; r < 4; r++)
                    Cb[(size_t)(rbase + mi * 16 + r) * ldc + col0 + ni * 16] =
                        acc[mi][ni][r] * scale;
    }
}

// ---- wave-level causal softmax of one row (register-resident) -----------

__device__ __forceinline__ void softmax_row(unsigned short* __restrict__ S,
                                            int row) {
    int lane = threadIdx.x & 63;
    int i = row & 2047;  // causal row index within batch
    unsigned short* s = S + (size_t)row * 2048;

    uint4 raw[4];
#pragma unroll
    for (int c = 0; c < 4; c++) raw[c] = ((const uint4*)s)[lane + c * 64];

    const float NEG = -1.0e30f;
    float p[32];
    float m = NEG;
#pragma unroll
    for (int c = 0; c < 4; c++) {
        const unsigned int* u = (const unsigned int*)&raw[c];
#pragma unroll
        for (int w = 0; w < 4; w++) {
            int j = c * 512 + lane * 8 + w * 2;
            float f0 = bf2f_hi(u[w] << 16);
            float f1 = bf2f_hi(u[w] & 0xffff0000u);
            f0 = (j <= i) ? f0 : NEG;
            f1 = (j + 1 <= i) ? f1 : NEG;
            p[c * 8 + w * 2] = f0;
            p[c * 8 + w * 2 + 1] = f1;
            m = fmaxf(m, fmaxf(f0, f1));
        }
    }
#pragma unroll
    for (int o = 32; o > 0; o >>= 1) m = fmaxf(m, __shfl_xor(m, o));

    float sum = 0.f;
#pragma unroll
    for (int t = 0; t < 32; t++) {
        p[t] = __expf(p[t] - m);
        sum += p[t];
    }
#pragma unroll
    for (int o = 32; o > 0; o >>= 1) sum += __shfl_xor(sum, o);
    float inv = 1.0f / sum;

#pragma unroll
    for (int c = 0; c < 4; c++) {
        uint4 out;
        unsigned int* u = (unsigned int*)&out;
#pragma unroll
        for (int w = 0; w < 4; w++) {
            unsigned int lo = f2bf(p[c * 8 + w * 2] * inv);
            unsigned int hi = f2bf(p[c * 8 + w * 2 + 1] * inv);
            u[w] = lo | (hi << 16);
        }
        ((uint4*)s)[lane + c * 64] = out;
    }
}

// ---- triangular job decode for the S stage ------------------------------

__device__ __forceinline__ void tri_decode(int r2, int& mb, int& nb) {
    mb = (int)((sqrtf(8.0f * r2 + 1.0f) - 1.0f) * 0.5f);
    while ((mb + 1) * (mb + 2) / 2 <= r2) mb++;
    while (mb * (mb + 1) / 2 > r2) mb--;
    nb = r2 - mb * (mb + 1) / 2;
}

// ---- the fused cooperative kernel (BK=32, 16KB LDS) ---------------------
// Grid sized by the host to maxActiveBlocks*numCUs (<=1024) so cooperative
// launch validation passes. All phase maps are grid-stride: correct for any
// grid size.

__global__ __launch_bounds__(256, 4) void fused(
    const float* __restrict__ x, const float* __restrict__ Wq,
    const float* __restrict__ Wk, const float* __restrict__ Wv,
    unsigned short* __restrict__ xb, unsigned short* __restrict__ wT,
    unsigned short* __restrict__ qk, unsigned short* __restrict__ S,
    unsigned short* __restrict__ vt, float* __restrict__ out) {
    cg::grid_group grid = cg::this_grid();
    __shared__ __align__(16) unsigned short smem[BM * 32 + BN * 32];  // 16 KB
    unsigned short* As = smem;
    unsigned short* Bs = smem + BM * 32;
    int b = blockIdx.x;
    int G = gridDim.x;
    int t = threadIdx.x;

    // ---- phase 0: x -> bf16 (grid-stride) + W^T bf16 --------------------
    for (int i = b * 256 + t; i < 2097152; i += G * 256) {
        float4 v = ((const float4*)x)[i];
        ushort4 o;
        o.x = f2bf(v.x);
        o.y = f2bf(v.y);
        o.z = f2bf(v.z);
        o.w = f2bf(v.w);
        ((ushort4*)xb)[i] = o;
    }
    {
        float* tile = (float*)smem;  // 32x33 fp32 = 4224 B, overlays As
        int tx = t & 31, ty = t >> 5;
        for (int w = b; w < 3072; w += G) {
            int z = w >> 10, r = w & 1023;
            int bx = (r & 31) * 32;  // input col (n)
            int by = (r >> 5) * 32;  // input row (k)
            const float* W = z == 0 ? Wq : (z == 1 ? Wk : Wv);
            __syncthreads();  // protect smem reuse across iterations
            for (int rr = 0; rr < 32; rr += 8)
                tile[(ty + rr) * 33 + tx] =
                    W[(size_t)(by + ty + rr) * 1024 + bx + tx];
            __syncthreads();
            unsigned short* o = wT + (size_t)z * 1024 * 1024;
            for (int rr = 0; rr < 32; rr += 8)
                o[(size_t)(bx + ty + rr) * 1024 + by + tx] =
                    f2bf(tile[tx * 33 + ty + rr]);
        }
    }
    grid.sync();

    // ---- phase 1: qk = xb @ [Wq|Wk] (1024 jobs) + vt = WvT @ xb^T (512) --
    for (int j = b; j < 1536; j += G) {
        if (j < 1024) {
            gemm_core<32>(As, Bs, xb, 1024, wT, 1024, qk, 2048, true, 1024,
                          1.0f, (j >> 4) * BM, (j & 15) * BN);
        } else {
            int r = j - 1024;
            gemm_core<32>(As, Bs, wT + 2 * 1024 * 1024, 1024, xb, 1024, vt,
                          8192, true, 1024, 1.0f, (r >> 6) * BM,
                          (r & 63) * BN);
        }
    }
    grid.sync();

    // ---- phase 2: S = scale * Q K^T, 544 lower-triangle jobs ------------
    for (int j = b; j < 544; j += G) {
        int bz = j / 136;
        int mb, nb;
        tri_decode(j - bz * 136, mb, nb);
        const unsigned short* Q = qk + (size_t)bz * 2048 * 2048;
        gemm_core<32>(As, Bs, Q, 2048, Q + 1024, 2048,
                      S + (size_t)bz * 2048 * 2048, 2048, true, 1024,
                      0.03125f, mb * BM, nb * BN);
    }
    grid.sync();

    // ---- phase 3: causal softmax, 8192 rows, 4 waves/block --------------
    for (int r = b * 4 + (t >> 6); r < 8192; r += G * 4) softmax_row(S, r);
    grid.sync();

    // ---- phase 4: O = P @ V, 512 jobs, kend-paired for per-CU balance ----
    for (int j = b; j < 512; j += G) {
        int mb, rem;
        if (j < 256) {
            mb = j >> 5;
            rem = j & 31;
        } else {
            mb = 15 - ((j - 256) >> 5);
            rem = (j - 256) & 31;
        }
        int bz = rem >> 3, nb = rem & 7;
        int kend = (mb + 1) * 128;  // P[i][j]==0 for j>i
        gemm_core<32>(As, Bs, S + (size_t)bz * 2048 * 2048, 2048,
                      vt + (size_t)bz * 2048, 8192,
                      out + (size_t)bz * 2048 * 1024, 1024, false, kend, 1.0f,
                      mb * BM, nb * BN);
    }
}

// ==== fallback path: the proven R5 5-dispatch pipeline (BK=64) ===========

__global__ __launch_bounds__(256) void prep_f(const float* __restrict__ x,
                                              const float* __restrict__ Wq,
                                              const float* __restrict__ Wk,
                                              const float* __restrict__ Wv,
                                              unsigned short* __restrict__ xb,
                                              unsigned short* __restrict__ wT) {
    __shared__ float tile[32][33];
    int bid = blockIdx.x;
    int tid = threadIdx.x;
    if (bid < 8192) {
        int i = bid * 256 + tid;
        float4 v = ((const float4*)x)[i];
        ushort4 o;
        o.x = f2bf(v.x);
        o.y = f2bf(v.y);
        o.z = f2bf(v.z);
        o.w = f2bf(v.w);
        ((ushort4*)xb)[i] = o;
    } else {
        int w = bid - 8192;
        int z = w >> 10;
        int r = w & 1023;
        int bx = (r & 31) * 32;
        int by = (r >> 5) * 32;
        const float* W = z == 0 ? Wq : (z == 1 ? Wk : Wv);
        int tx = tid & 31, ty = tid >> 5;
        for (int rr = 0; rr < 32; rr += 8)
            tile[ty + rr][tx] = W[(size_t)(by + ty + rr) * 1024 + bx + tx];
        __syncthreads();
        unsigned short* o = wT + (size_t)z * 1024 * 1024;
        for (int rr = 0; rr < 32; rr += 8)
            o[(size_t)(bx + ty + rr) * 1024 + by + tx] = f2bf(tile[tx][ty + rr]);
    }
}

__global__ __launch_bounds__(256, 4) void gemm_qk_f(
    const unsigned short* __restrict__ xb, const unsigned short* __restrict__ wT,
    unsigned short* __restrict__ qk) {
    __shared__ __align__(16) unsigned short As[BM * 64], Bs[BN * 64];
    gemm_core<64>(As, Bs, xb, 1024, wT, 1024, qk, 2048, true, 1024, 1.0f,
                  blockIdx.y * BM, blockIdx.x * BN);
}

__global__ __launch_bounds__(256, 4) void gemm_s_f(
    const unsigned short* __restrict__ qk, unsigned short* __restrict__ S) {
    __shared__ __align__(16) unsigned short As[BM * 64], Bs[BN * 64];
    int bz = blockIdx.x / 136;
    int mb, nb;
    tri_decode(blockIdx.x - bz * 136, mb, nb);
    const unsigned short* Q = qk + (size_t)bz * 2048 * 2048;
    gemm_core<64>(As, Bs, Q, 2048, Q + 1024, 2048, S + (size_t)bz * 2048 * 2048,
                  2048, true, 1024, 0.03125f, mb * BM, nb * BN);
}

__global__ __launch_bounds__(256, 4) void sm_vt_f(
    unsigned short* __restrict__ S, const unsigned short* __restrict__ wTv,
    const unsigned short* __restrict__ xb, unsigned short* __restrict__ vt) {
    __shared__ __align__(16) unsigned short As[BM * 64], Bs[BN * 64];
    int bid = blockIdx.x;
    if (bid < 512) {
        gemm_core<64>(As, Bs, wTv, 1024, xb, 1024, vt, 8192, true, 1024, 1.0f,
                      (bid >> 6) * BM, (bid & 63) * BN);
        return;
    }
    int row = (bid - 512) * 4 + (threadIdx.x >> 6);
    softmax_row(S, row);
    softmax_row(S, row + 4096);
}

__global__ __launch_bounds__(256, 4) void gemm_pv_f(
    const unsigned short* __restrict__ S, const unsigned short* __restrict__ vt,
    float* __restrict__ out) {
    __shared__ __align__(16) unsigned short As[BM * 64], Bs[BN * 64];
    int bz = blockIdx.z;
    int mb = gridDim.y - 1 - blockIdx.y;
    int m0 = mb * BM;
    int kend = m0 + BM < 2048 ? m0 + BM : 2048;
    gemm_core<64>(As, Bs, S + (size_t)bz * 2048 * 2048, 2048,
                  vt + (size_t)bz * 2048, 8192, out + (size_t)bz * 2048 * 1024,
                  1024, false, kend, 1.0f, m0, blockIdx.x * BN);
}

// ---- launch -------------------------------------------------------------

extern "C" void kernel_launch(void* const* d_in, const int* in_sizes, int n_in,
                              void* d_out, int out_size, void* d_ws,
                              size_t ws_size, hipStream_t stream) {
    const float* x = (const float*)d_in[0];
    const float* Wq = (const float*)d_in[1];
    const float* Wk = (const float*)d_in[2];
    const float* Wv = (const float*)d_in[3];
    // causal_mask (d_in[4]) is always 1 in this problem — hardcoded causal.

    char* ws = (char*)d_ws;
    // layout (bytes):
    //   qk [8192][2048] bf16  : 0        .. 33554432   (Q cols 0..1023, K cols 1024..2047)
    //   S  [4][2048][2048]    : 33554432 .. 67108864
    //   vt [1024][8192] bf16  : 67108864 .. 83886080   (V^T, batches side-by-side cols)
    //   xb [8192][1024] bf16  : 83886080 .. 100663296
    //   wT [3][1024][1024]    : 100663296.. 106954752
    unsigned short* qk = (unsigned short*)(ws);
    unsigned short* S = (unsigned short*)(ws + 33554432);
    unsigned short* vt = (unsigned short*)(ws + 67108864);
    unsigned short* xb = (unsigned short*)(ws + 83886080);
    unsigned short* wT = (unsigned short*)(ws + 100663296);
    float* outp = (float*)d_out;

    // Host-side capability probe (capture-safe: no stream ops). Same result
    // every call — no state guards.
    int dev = 0;
    hipGetDevice(&dev);
    int coop = 0, cus = 0, maxb = 0;
    hipDeviceGetAttribute(&coop, hipDeviceAttributeCooperativeLaunch, dev);
    hipDeviceGetAttribute(&cus, hipDeviceAttributeMultiprocessorCount, dev);
    hipOccupancyMaxActiveBlocksPerMultiprocessor(&maxb, fused, 256, 0);
    long long cap = (long long)maxb * cus;
    int grid = cap > 1024 ? 1024 : (int)cap;

    if (coop && grid >= 512) {
        void* args[] = {(void*)&x,  (void*)&Wq, (void*)&Wk, (void*)&Wv,
                        (void*)&xb, (void*)&wT, (void*)&qk, (void*)&S,
                        (void*)&vt, (void*)&outp};
        hipError_t e = hipLaunchCooperativeKernel((const void*)fused,
                                                  dim3(grid), dim3(256), args,
                                                  0, stream);
        if (e == hipSuccess) return;
    }

    // fallback: proven 5-dispatch pipeline
    prep_f<<<11264, 256, 0, stream>>>(x, Wq, Wk, Wv, xb, wT);
    gemm_qk_f<<<dim3(16, 64), 256, 0, stream>>>(xb, wT, qk);
    gemm_s_f<<<544, 256, 0, stream>>>(qk, S);
    sm_vt_f<<<2560, 256, 0, stream>>>(S, wT + 2 * 1024 * 1024, xb, vt);
    gemm_pv_f<<<dim3(8, 16, 4), 256, 0, stream>>>(S, vt, outp);
}

// Round 9
// 249.698 us; speedup vs baseline: 2.1733x; 2.1733x over previous
//
#include <hip/hip_runtime.h>
#include <hip/hip_bf16.h>
#include <stdint.h>

#define BM 128
#define BN 128
#define BK 64

typedef __attribute__((ext_vector_type(8))) short bf16x8;
typedef __attribute__((ext_vector_type(4))) float floatx4;

// ---- helpers ------------------------------------------------------------

__device__ __forceinline__ unsigned short f2bf(float f) {
    unsigned int x;
    __builtin_memcpy(&x, &f, 4);
    unsigned int r = (x + 0x7fffu + ((x >> 16) & 1u)) >> 16;  // RNE
    return (unsigned short)r;
}

__device__ __forceinline__ float bf2f_hi(unsigned int u_hi_masked) {
    float f;
    __builtin_memcpy(&f, &u_hi_masked, 4);
    return f;
}

// async global->LDS, 16B per lane.  LDS dest must be wave-uniform base + lane*16.
__device__ __forceinline__ void async_copy16(const void* g, void* l) {
    __builtin_amdgcn_global_load_lds(
        (const __attribute__((address_space(1))) void*)(uintptr_t)g,
        (__attribute__((address_space(3))) void*)(uint32_t)(uintptr_t)l,
        16, 0, 0);
}

// ---- prep: fp32->bf16 convert of x  +  W^T bf16 of Wq/Wk/Wv -------------

__global__ __launch_bounds__(256) void prep(const float* __restrict__ x,
                                            const float* __restrict__ Wq,
                                            const float* __restrict__ Wk,
                                            const float* __restrict__ Wv,
                                            unsigned short* __restrict__ xb,
                                            unsigned short* __restrict__ wT) {
    __shared__ float tile[32][33];
    int bid = blockIdx.x;
    int tid = threadIdx.x;
    if (bid < 8192) {  // cvt: 8192 blocks x 256 threads x float4
        int i = bid * 256 + tid;
        float4 v = ((const float4*)x)[i];
        ushort4 o;
        o.x = f2bf(v.x);
        o.y = f2bf(v.y);
        o.z = f2bf(v.z);
        o.w = f2bf(v.w);
        ((ushort4*)xb)[i] = o;
    } else {  // transpose W: 3 x 1024 blocks, 32x32 tiles
        int w = bid - 8192;
        int z = w >> 10;
        int r = w & 1023;
        int bx = (r & 31) * 32;  // input col (n)
        int by = (r >> 5) * 32;  // input row (k)
        const float* W = z == 0 ? Wq : (z == 1 ? Wk : Wv);
        int tx = tid & 31, ty = tid >> 5;  // 32x8
        for (int rr = 0; rr < 32; rr += 8)
            tile[ty + rr][tx] = W[(size_t)(by + ty + rr) * 1024 + bx + tx];
        __syncthreads();
        unsigned short* o = wT + (size_t)z * 1024 * 1024;
        for (int rr = 0; rr < 32; rr += 8)
            o[(size_t)(bx + ty + rr) * 1024 + by + tx] = f2bf(tile[tx][ty + rr]);
    }
}

// ---- GEMM core: C[m][n] = scale * sum_k A[m][k] * Bt[n][k] --------------
// m97-style: 128x128 tile, BK=64, 4 waves (2x2), 32 16x16x32 bf16 MFMA/wave
// per k-iter, global_load_lds width-16 staging into unpadded row-major LDS
// [row][64] (layout = lane order, a hard requirement).
// Placement model (validated R5/R7): stage time ~= max per-CU BK64-iters
// x 0.805us; blocks land round-robin on CUs (block l -> CU l%256).

__device__ __forceinline__ void gemm_core(const unsigned short* __restrict__ A,
                                          int lda,
                                          const unsigned short* __restrict__ B,
                                          int ldb, void* __restrict__ C,
                                          int ldc, bool out_bf16, int kend,
                                          float scale, int m0, int n0) {
    __shared__ __align__(16) unsigned short As[BM * BK];  // 16 KB
    __shared__ __align__(16) unsigned short Bs[BN * BK];  // 16 KB

    int tid = threadIdx.x;
    int lane = tid & 63;
    int wave = tid >> 6;
    int wm = (wave >> 1) * 64;
    int wn = (wave & 1) * 64;
    int fr = lane & 15;  // fragment row (m) / col (n)
    int kq = lane >> 4;  // k-quad

    floatx4 acc[4][4] = {};

    for (int k0 = 0; k0 < kend; k0 += BK) {
#pragma unroll
        for (int q = 0; q < 4; q++) {
            int c = tid + q * 256;
            int r = c >> 3, ko = (c & 7) * 8;
            async_copy16(A + (size_t)(m0 + r) * lda + k0 + ko, &As[c * 8]);
            async_copy16(B + (size_t)(n0 + r) * ldb + k0 + ko, &Bs[c * 8]);
        }
        __syncthreads();  // drains vmcnt before LDS reads

#pragma unroll
        for (int kh = 0; kh < 2; kh++) {
            int kc = kh * 4 + kq;
            bf16x8 af[4], bfg[4];
#pragma unroll
            for (int mi = 0; mi < 4; mi++)
                af[mi] = *(const bf16x8*)&As[(wm + mi * 16 + fr) * BK + kc * 8];
#pragma unroll
            for (int ni = 0; ni < 4; ni++)
                bfg[ni] = *(const bf16x8*)&Bs[(wn + ni * 16 + fr) * BK + kc * 8];
#pragma unroll
            for (int mi = 0; mi < 4; mi++)
#pragma unroll
                for (int ni = 0; ni < 4; ni++)
                    acc[mi][ni] = __builtin_amdgcn_mfma_f32_16x16x32_bf16(
                        af[mi], bfg[ni], acc[mi][ni], 0, 0, 0);
        }
        __syncthreads();  // protect LDS before next stage
    }

    // epilogue: C/D layout col=lane&15, row=(lane>>4)*4+reg  (m89/m91-verified)
    int col0 = n0 + wn + fr;
    int rbase = m0 + wm + kq * 4;
    if (out_bf16) {
        unsigned short* Cb = (unsigned short*)C;
#pragma unroll
        for (int mi = 0; mi < 4; mi++)
#pragma unroll
            for (int ni = 0; ni < 4; ni++)
#pragma unroll
                for (int r = 0; r < 4; r++)
                    Cb[(size_t)(rbase + mi * 16 + r) * ldc + col0 + ni * 16] =
                        f2bf(acc[mi][ni][r] * scale);
    } else {
        float* Cb = (float*)C;
#pragma unroll
        for (int mi = 0; mi < 4; mi++)
#pragma unroll
            for (int ni = 0; ni < 4; ni++)
#pragma unroll
                for (int r = 0; r < 4; r++)
                    Cb[(size_t)(rbase + mi * 16 + r) * ldc + col0 + ni * 16] =
                        acc[mi][ni][r] * scale;
    }
}

// ---- triangular job decode for the S stage ------------------------------

__device__ __forceinline__ void tri_decode(int r2, int& mb, int& nb) {
    mb = (int)((sqrtf(8.0f * r2 + 1.0f) - 1.0f) * 0.5f);
    while ((mb + 1) * (mb + 2) / 2 <= r2) mb++;
    while (mb * (mb + 1) / 2 > r2) mb--;
    nb = r2 - mb * (mb + 1) / 2;
}

// ---- stage B: qk = xb @ [Wq|Wk]  (M=8192, N=2048, K=1024) ---------------
// 1024 blocks = 4/CU x 16 iters = 64 iters/CU, uniform.

__global__ __launch_bounds__(256, 4) void gemm_qk(
    const unsigned short* __restrict__ xb, const unsigned short* __restrict__ wT,
    unsigned short* __restrict__ qk) {
    gemm_core(xb, 1024, wT, 1024, qk, 2048, true, 1024, 1.0f,
              blockIdx.y * BM, blockIdx.x * BN);
}

// ---- stage C: S = scale * Q K^T, lower-triangle blocks only -------------
// 544 blocks; max CU gets 3 blocks = 48 iters.

__global__ __launch_bounds__(256, 4) void gemm_s(
    const unsigned short* __restrict__ qk, unsigned short* __restrict__ S) {
    int bz = blockIdx.x / 136;
    int mb, nb;
    tri_decode(blockIdx.x - bz * 136, mb, nb);
    const unsigned short* Q = qk + (size_t)bz * 2048 * 2048;
    gemm_core(Q, 2048, Q + 1024, 2048, S + (size_t)bz * 2048 * 2048, 2048,
              true, 1024, 0.03125f, mb * BM, nb * BN);
}

// ---- stage D: softmax (causal, in place)  MERGED WITH  vt = WvT @ xb^T --
// Softmax: ONE row per wave (2048 blocks x 4 waves = 8192 rows exactly).
// R8 bug: a two-rows-per-wave loop here wrote rows 8192..12287 — 16 MB past
// S, straight into vt. Keep the row map 1:1 with the grid.

__global__ __launch_bounds__(256, 4) void sm_vt(
    unsigned short* __restrict__ S, const unsigned short* __restrict__ wTv,
    const unsigned short* __restrict__ xb, unsigned short* __restrict__ vt) {
    int bid = blockIdx.x;
    if (bid < 512) {  // vt: 8 m-blocks x 64 n-blocks (M=1024 WvT, N=8192 xb)
        gemm_core(wTv, 1024, xb, 1024, vt, 8192, true, 1024, 1.0f,
                  (bid >> 6) * BM, (bid & 63) * BN);
        return;
    }
    // softmax: one wave per row, full row in registers (32 f32/lane)
    int lane = threadIdx.x & 63;
    int row = (bid - 512) * 4 + (threadIdx.x >> 6);  // 0..8191
    int i = row & 2047;  // causal row index within batch
    unsigned short* s = S + (size_t)row * 2048;

    uint4 raw[4];
#pragma unroll
    for (int c = 0; c < 4; c++) raw[c] = ((const uint4*)s)[lane + c * 64];

    const float NEG = -1.0e30f;
    float p[32];
    float m = NEG;
#pragma unroll
    for (int c = 0; c < 4; c++) {
        const unsigned int* u = (const unsigned int*)&raw[c];
#pragma unroll
        for (int w = 0; w < 4; w++) {
            int j = c * 512 + lane * 8 + w * 2;
            float f0 = bf2f_hi(u[w] << 16);
            float f1 = bf2f_hi(u[w] & 0xffff0000u);
            f0 = (j <= i) ? f0 : NEG;
            f1 = (j + 1 <= i) ? f1 : NEG;
            p[c * 8 + w * 2] = f0;
            p[c * 8 + w * 2 + 1] = f1;
            m = fmaxf(m, fmaxf(f0, f1));
        }
    }
#pragma unroll
    for (int o = 32; o > 0; o >>= 1) m = fmaxf(m, __shfl_xor(m, o));

    float sum = 0.f;
#pragma unroll
    for (int t = 0; t < 32; t++) {
        p[t] = __expf(p[t] - m);
        sum += p[t];
    }
#pragma unroll
    for (int o = 32; o > 0; o >>= 1) sum += __shfl_xor(sum, o);
    float inv = 1.0f / sum;

#pragma unroll
    for (int c = 0; c < 4; c++) {
        uint4 out;
        unsigned int* u = (unsigned int*)&out;
#pragma unroll
        for (int w = 0; w < 4; w++) {
            unsigned int lo = f2bf(p[c * 8 + w * 2] * inv);
            unsigned int hi = f2bf(p[c * 8 + w * 2 + 1] * inv);
            u[w] = lo | (hi << 16);
        }
        ((uint4*)s)[lane + c * 64] = out;
    }
}

// ---- stage E: O = P @ V, complementary kend pairing ---------------------
// Round-robin block->CU: CU c gets blocks c and c+256. Map b<256 -> j=b
// (mb=j>>5 in 0..7), b>=256 -> j=767-b (mb in 8..15): per-CU iters
// = 2(mb+1) + 2(16-mb) = 34, uniform (vs 64 worst-case with same-mb pairing
// — that mispairing alone made PV 51.7us in R5).

__global__ __launch_bounds__(256, 4) void gemm_pv(
    const unsigned short* __restrict__ S, const unsigned short* __restrict__ vt,
    float* __restrict__ out) {
    int b = blockIdx.x;
    int j = b < 256 ? b : 767 - b;
    int mb = j >> 5;
    int rem = j & 31;
    int bz = rem >> 3, nb = rem & 7;
    int kend = (mb + 1) * 128;  // P[i][j]==0 for j>i
    gemm_core(S + (size_t)bz * 2048 * 2048, 2048, vt + (size_t)bz * 2048, 8192,
              out + (size_t)bz * 2048 * 1024, 1024, false, kend, 1.0f,
              mb * BM, nb * BN);
}

// ---- launch -------------------------------------------------------------

extern "C" void kernel_launch(void* const* d_in, const int* in_sizes, int n_in,
                              void* d_out, int out_size, void* d_ws,
                              size_t ws_size, hipStream_t stream) {
    const float* x = (const float*)d_in[0];
    const float* Wq = (const float*)d_in[1];
    const float* Wk = (const float*)d_in[2];
    const float* Wv = (const float*)d_in[3];
    // causal_mask (d_in[4]) is always 1 in this problem — hardcoded causal.

    char* ws = (char*)d_ws;
    // layout (bytes):
    //   qk [8192][2048] bf16  : 0        .. 33554432   (Q cols 0..1023, K cols 1024..2047)
    //   S  [4][2048][2048]    : 33554432 .. 67108864
    //   vt [1024][8192] bf16  : 67108864 .. 83886080   (V^T, batches side-by-side cols)
    //   xb [8192][1024] bf16  : 83886080 .. 100663296
    //   wT [3][1024][1024]    : 100663296.. 106954752
    unsigned short* qk = (unsigned short*)(ws);
    unsigned short* S = (unsigned short*)(ws + 33554432);
    unsigned short* vt = (unsigned short*)(ws + 67108864);
    unsigned short* xb = (unsigned short*)(ws + 83886080);
    unsigned short* wT = (unsigned short*)(ws + 100663296);

    // A. x->bf16 (8192 blocks) + W->W^T bf16 (3072 blocks), one dispatch
    prep<<<11264, 256, 0, stream>>>(x, Wq, Wk, Wv, xb, wT);
    // B. qk = xb @ [Wq|Wk]   (M=8192, N=2048, K=1024) — 1024 blocks
    gemm_qk<<<dim3(16, 64), 256, 0, stream>>>(xb, wT, qk);
    // C. S = scale * Q K^T — 544 lower-triangle blocks only
    gemm_s<<<544, 256, 0, stream>>>(qk, S);
    // D. softmax (2048 light blocks) + vt GEMM (512 blocks), one dispatch
    sm_vt<<<2560, 256, 0, stream>>>(S, wT + 2 * 1024 * 1024, xb, vt);
    // E. O = P @ V — 512 blocks, complementary kend pairing
    gemm_pv<<<512, 256, 0, stream>>>(S, vt, (float*)d_out);
}